// Round 1
// baseline (4489.831 us; speedup 1.0000x reference)
//
#include <hip/hip_runtime.h>

#define BROWS  32768
#define DDIM   512
#define NCODES 8192
#define TM     128
#define TN     128
#define KB     16

__device__ __forceinline__ float wave_sum(float v) {
#pragma unroll
  for (int o = 32; o > 0; o >>= 1) v += __shfl_xor(v, o, 64);
  return v;
}

// One wave per row: L2-normalize rows of e (NCODES x DDIM) into en.
__global__ __launch_bounds__(256) void norm_rows_kernel(const float* __restrict__ e,
                                                        float* __restrict__ en) {
  int w = threadIdx.x >> 6, lane = threadIdx.x & 63;
  int row = blockIdx.x * 4 + w;
  const float4* src = (const float4*)(e + (size_t)row * DDIM);
  float4 a = src[lane];
  float4 b = src[lane + 64];
  float s = a.x * a.x + a.y * a.y + a.z * a.z + a.w * a.w
          + b.x * b.x + b.y * b.y + b.z * b.z + b.w * b.w;
  s = wave_sum(s);
  float inv = 1.0f / fmaxf(sqrtf(s), 1e-12f);
  float4 oa = make_float4(a.x * inv, a.y * inv, a.z * inv, a.w * inv);
  float4 ob = make_float4(b.x * inv, b.y * inv, b.z * inv, b.w * inv);
  float4* dst = (float4*)(en + (size_t)row * DDIM);
  dst[lane] = oa;
  dst[lane + 64] = ob;
}

// Fused fp32 GEMM + per-row argmax. 128x128 tile, 8x8 micro-tile, KB=16.
// argmax(z . en_k) == argmax(cos sim) since |z| is constant per row.
__global__ __launch_bounds__(256) void gemm_argmax_kernel(const float* __restrict__ z,
                                                          const float* __restrict__ en,
                                                          int* __restrict__ out_idx) {
  __shared__ float As[KB][TM + 4];  // As[k][m] = z[row0+m][k0+k]   (pad 4: 2-way max on store)
  __shared__ float Bs[KB][TN + 4];  // Bs[k][n] = en[ct*TN+n][k0+k]
  __shared__ float rv[TM][16];
  __shared__ int   ri[TM][16];
  const int t  = threadIdx.x;
  const int tx = t & 15;
  const int ty = t >> 4;
  const int row0 = blockIdx.x * TM;
  const int m  = t >> 2;   // 0..63 staging row
  const int f4 = t & 3;    // 0..3  staging float4 within KB

  float bestv[8];
  int   bestn[8];
#pragma unroll
  for (int i = 0; i < 8; ++i) { bestv[i] = -3.0e38f; bestn[i] = 0; }

  for (int ct = 0; ct < NCODES / TN; ++ct) {
    float acc[8][8];
#pragma unroll
    for (int i = 0; i < 8; ++i)
#pragma unroll
      for (int j = 0; j < 8; ++j) acc[i][j] = 0.0f;

    for (int kt = 0; kt < DDIM / KB; ++kt) {
      const int k0 = kt * KB;
      __syncthreads();
      {
        const float* zb = z + (size_t)(row0 + m) * DDIM + k0 + f4 * 4;
        float4 v0 = *(const float4*)zb;
        float4 v1 = *(const float4*)(zb + (size_t)64 * DDIM);
        const float* eb = en + (size_t)(ct * TN + m) * DDIM + k0 + f4 * 4;
        float4 w0 = *(const float4*)eb;
        float4 w1 = *(const float4*)(eb + (size_t)64 * DDIM);
        const int kk = f4 * 4;
        As[kk + 0][m] = v0.x; As[kk + 1][m] = v0.y; As[kk + 2][m] = v0.z; As[kk + 3][m] = v0.w;
        As[kk + 0][m + 64] = v1.x; As[kk + 1][m + 64] = v1.y; As[kk + 2][m + 64] = v1.z; As[kk + 3][m + 64] = v1.w;
        Bs[kk + 0][m] = w0.x; Bs[kk + 1][m] = w0.y; Bs[kk + 2][m] = w0.z; Bs[kk + 3][m] = w0.w;
        Bs[kk + 0][m + 64] = w1.x; Bs[kk + 1][m + 64] = w1.y; Bs[kk + 2][m + 64] = w1.z; Bs[kk + 3][m + 64] = w1.w;
      }
      __syncthreads();
#pragma unroll
      for (int k = 0; k < KB; ++k) {
        // conflict-free reads: A broadcast (4 addrs/wave), B 2-way (free)
        float4 a0 = *(const float4*)&As[k][ty * 8];
        float4 a1 = *(const float4*)&As[k][ty * 8 + 4];
        float4 b0 = *(const float4*)&Bs[k][tx * 4];
        float4 b1 = *(const float4*)&Bs[k][64 + tx * 4];
        float a[8] = {a0.x, a0.y, a0.z, a0.w, a1.x, a1.y, a1.z, a1.w};
        float b[8] = {b0.x, b0.y, b0.z, b0.w, b1.x, b1.y, b1.z, b1.w};
#pragma unroll
        for (int i = 0; i < 8; ++i)
#pragma unroll
          for (int j = 0; j < 8; ++j)
            acc[i][j] = fmaf(a[i], b[j], acc[i][j]);
      }
    }
    const int nb = ct * TN;
#pragma unroll
    for (int i = 0; i < 8; ++i) {
#pragma unroll
      for (int j = 0; j < 8; ++j) {
        int n = nb + ((j < 4) ? (tx * 4 + j) : (64 + tx * 4 + (j - 4)));
        if (acc[i][j] > bestv[i]) { bestv[i] = acc[i][j]; bestn[i] = n; }
      }
    }
  }
  // cross-thread argmax per row (16 tx threads share each row); tie -> lower index
#pragma unroll
  for (int i = 0; i < 8; ++i) { rv[ty * 8 + i][tx] = bestv[i]; ri[ty * 8 + i][tx] = bestn[i]; }
  __syncthreads();
  if (t < TM) {
    float bv = rv[t][0];
    int   bi = ri[t][0];
#pragma unroll
    for (int x = 1; x < 16; ++x) {
      float v = rv[t][x]; int n = ri[t][x];
      if (v > bv || (v == bv && n < bi)) { bv = v; bi = n; }
    }
    out_idx[row0 + t] = bi;
  }
}

// One wave per row: normalize z on the fly, gather q=en[idx], write z_q_ste,
// accumulate sum (zn - q)^2, counts, and indices-as-float.
__global__ __launch_bounds__(256) void finalize_kernel(const float* __restrict__ z,
                                                       const float* __restrict__ en,
                                                       const int* __restrict__ idxs,
                                                       float* __restrict__ out_q,
                                                       float* __restrict__ out_i,
                                                       float* __restrict__ counts,
                                                       float* __restrict__ loss) {
  int w = threadIdx.x >> 6, lane = threadIdx.x & 63;
  int row = blockIdx.x * 4 + w;
  const float4* zr = (const float4*)(z + (size_t)row * DDIM);
  float4 a = zr[lane], b = zr[lane + 64];
  float s = a.x * a.x + a.y * a.y + a.z * a.z + a.w * a.w
          + b.x * b.x + b.y * b.y + b.z * b.z + b.w * b.w;
  s = wave_sum(s);
  float inv = 1.0f / fmaxf(sqrtf(s), 1e-12f);
  int k = idxs[row];
  const float4* qr = (const float4*)(en + (size_t)k * DDIM);
  float4 qa = qr[lane], qb = qr[lane + 64];
  float d = 0.0f;
  float4 oa, ob;
  {
    float zn;
    zn = a.x * inv; oa.x = zn + (qa.x - zn); d += (zn - qa.x) * (zn - qa.x);
    zn = a.y * inv; oa.y = zn + (qa.y - zn); d += (zn - qa.y) * (zn - qa.y);
    zn = a.z * inv; oa.z = zn + (qa.z - zn); d += (zn - qa.z) * (zn - qa.z);
    zn = a.w * inv; oa.w = zn + (qa.w - zn); d += (zn - qa.w) * (zn - qa.w);
    zn = b.x * inv; ob.x = zn + (qb.x - zn); d += (zn - qb.x) * (zn - qb.x);
    zn = b.y * inv; ob.y = zn + (qb.y - zn); d += (zn - qb.y) * (zn - qb.y);
    zn = b.z * inv; ob.z = zn + (qb.z - zn); d += (zn - qb.z) * (zn - qb.z);
    zn = b.w * inv; ob.w = zn + (qb.w - zn); d += (zn - qb.w) * (zn - qb.w);
  }
  float4* orow = (float4*)(out_q + (size_t)row * DDIM);
  orow[lane] = oa;
  orow[lane + 64] = ob;
  d = wave_sum(d);
  if (lane == 0) {
    atomicAdd(loss, d);
    atomicAdd(&counts[k], 1.0f);
    out_i[row] = (float)k;
  }
}

__global__ __launch_bounds__(256) void scalars_kernel(const float* __restrict__ counts,
                                                      const float* __restrict__ loss,
                                                      float* __restrict__ o) {
  __shared__ float se[256], su[256];
  int t = threadIdx.x;
  float ent = 0.0f, utl = 0.0f;
  for (int i = t; i < NCODES; i += 256) {
    float c = counts[i];
    float p = c * (1.0f / (float)BROWS);
    ent -= p * logf(p + 1e-10f);
    utl += (c > 0.0f) ? 1.0f : 0.0f;
  }
  se[t] = ent; su[t] = utl;
  __syncthreads();
  for (int s2 = 128; s2 > 0; s2 >>= 1) {
    if (t < s2) { se[t] += se[t + s2]; su[t] += su[t + s2]; }
    __syncthreads();
  }
  if (t == 0) {
    float mse = (*loss) * (1.0f / (float)(BROWS * DDIM));
    o[0] = 0.25f * mse;   // commitment
    o[1] = mse;           // codebook
    o[2] = expf(se[0]);   // perplexity
    o[3] = su[0] * (1.0f / (float)NCODES);  // utilization
  }
}

extern "C" void kernel_launch(void* const* d_in, const int* in_sizes, int n_in,
                              void* d_out, int out_size, void* d_ws, size_t ws_size,
                              hipStream_t stream) {
  const float* z = (const float*)d_in[0];
  const float* e = (const float*)d_in[1];
  float* out = (float*)d_out;
  float* ws = (float*)d_ws;

  float* en     = ws;                                    // NCODES*DDIM fp32 (16.8 MB)
  int*   idxs   = (int*)(ws + (size_t)NCODES * DDIM);    // BROWS ints
  float* counts = ws + (size_t)NCODES * DDIM + BROWS;    // NCODES fp32
  float* loss   = counts + NCODES;                       // 1 fp32

  float* out_q = out;                                    // BROWS*DDIM
  float* out_i = out + (size_t)BROWS * DDIM;             // BROWS (indices as float)
  float* out_s = out_i + BROWS;                          // 4 scalars

  norm_rows_kernel<<<NCODES / 4, 256, 0, stream>>>(e, en);
  hipMemsetAsync(counts, 0, (NCODES + 1) * sizeof(float), stream);
  gemm_argmax_kernel<<<BROWS / TM, 256, 0, stream>>>(z, en, idxs);
  finalize_kernel<<<BROWS / 4, 256, 0, stream>>>(z, en, idxs, out_q, out_i, counts, loss);
  scalars_kernel<<<1, 256, 0, stream>>>(counts, loss, out_s);
}

// Round 2
// 2750.002 us; speedup vs baseline: 1.6327x; 1.6327x over previous
//
#include <hip/hip_runtime.h>

#define BROWS  32768
#define DDIM   512
#define NCODES 8192
#define NCHUNK 4
#define CHUNKN (NCODES / NCHUNK)   // 2048
#define TM     128
#define TN     128
#define BK     32
#define MARGIN 2e-5f

typedef unsigned short ushort_t;
typedef unsigned int   uint_t;
typedef __attribute__((ext_vector_type(8))) short  short8;
typedef __attribute__((ext_vector_type(4))) float  floatx4;

__device__ __forceinline__ float wave_sum(float v) {
#pragma unroll
  for (int o = 32; o > 0; o >>= 1) v += __shfl_xor(v, o, 64);
  return v;
}

__device__ __forceinline__ floatx4 mfma16(short8 a, short8 b, floatx4 c) {
  return __builtin_amdgcn_mfma_f32_16x16x32_bf16(a, b, c, 0, 0, 0);
}

// async global->LDS, 16B per lane; lds dst must be wave-uniform base (+lane*16 by HW)
__device__ __forceinline__ void ld2lds16(const ushort_t* g, ushort_t* l) {
  __builtin_amdgcn_global_load_lds((__attribute__((address_space(1))) void*)g,
                                   (__attribute__((address_space(3))) void*)l,
                                   16, 0, 0);
}

__device__ __forceinline__ void split1(float v, ushort_t& h, ushort_t& l) {
  uint_t u  = __float_as_uint(v);
  uint_t hb = (u + 0x7FFFu + ((u >> 16) & 1u)) >> 16;   // RNE
  h = (ushort_t)hb;
  float r = v - __uint_as_float(hb << 16);               // exact (Sterbenz)
  uint_t u2 = __float_as_uint(r);
  l = (ushort_t)((u2 + 0x7FFFu + ((u2 >> 16) & 1u)) >> 16);
}

// Normalize rows of x (4 rows/block, wave per row); write fp32 (optional) + bf16 hi/lo.
__global__ __launch_bounds__(256) void prep_split_kernel(const float* __restrict__ x,
                                                         float* __restrict__ xn,
                                                         ushort_t* __restrict__ xh,
                                                         ushort_t* __restrict__ xl) {
  const int w = threadIdx.x >> 6, lane = threadIdx.x & 63;
  const size_t row = (size_t)blockIdx.x * 4 + w;
  const float4* src = (const float4*)(x + row * DDIM);
  float4 a = src[lane], b = src[lane + 64];
  float s = a.x*a.x + a.y*a.y + a.z*a.z + a.w*a.w
          + b.x*b.x + b.y*b.y + b.z*b.z + b.w*b.w;
  s = wave_sum(s);
  const float inv = 1.0f / fmaxf(sqrtf(s), 1e-12f);
  a.x *= inv; a.y *= inv; a.z *= inv; a.w *= inv;
  b.x *= inv; b.y *= inv; b.z *= inv; b.w *= inv;
  if (xn) {
    float4* dst = (float4*)(xn + row * DDIM);
    dst[lane] = a; dst[lane + 64] = b;
  }
  ushort4 h0, l0, h1, l1;
  split1(a.x, h0.x, l0.x); split1(a.y, h0.y, l0.y);
  split1(a.z, h0.z, l0.z); split1(a.w, h0.w, l0.w);
  split1(b.x, h1.x, l1.x); split1(b.y, h1.y, l1.y);
  split1(b.z, h1.z, l1.z); split1(b.w, h1.w, l1.w);
  ushort4* ph = (ushort4*)(xh + row * DDIM);
  ushort4* pl = (ushort4*)(xl + row * DDIM);
  ph[lane] = h0; ph[lane + 64] = h1;
  pl[lane] = l0; pl[lane + 64] = l1;
}

// bf16x2 (3-MFMA) GEMM over one N-chunk, tracking per-row top1 (v,i) + top2 (v).
__global__ __launch_bounds__(256, 2) void gemm3_kernel(
    const ushort_t* __restrict__ zh, const ushort_t* __restrict__ zl,
    const ushort_t* __restrict__ eh, const ushort_t* __restrict__ el,
    float* __restrict__ pv1, int* __restrict__ pi1, float* __restrict__ pv2) {
  __shared__ union {
    ushort_t stg[4][TM * BK];                       // Ah Al Bh Bl : 4 x 8 KB
    struct { float v1[TM][33]; float v2[TM][33]; int i1[TM][33]; } red;
  } u;
  const int t = threadIdx.x;
  const int w = t >> 6;            // wave 0..3
  const int lane = t & 63;
  const int wm = w >> 1, wn = w & 1;
  const int col = lane & 15;
  const int quad = lane >> 4;
  const int chunk = blockIdx.x;
  const int row0 = blockIdx.y * TM;

  // staging: wave w fills u.stg[w]; per-lane source: row = base + lane/4, 16B chunk lane%4
  const ushort_t* gsrcA = (w == 0 ? zh : zl)
      + (size_t)(row0 + (lane >> 2)) * DDIM + (lane & 3) * 8;
  const ushort_t* eb = (w == 2) ? eh : el;
  ushort_t* ldst = u.stg[w];

  float tv1[16], tv2[16]; int ti1[16];
#pragma unroll
  for (int s = 0; s < 16; ++s) { tv1[s] = -3.0e38f; tv2[s] = -3.0e38f; ti1[s] = 0; }

  for (int ct = 0; ct < CHUNKN / TN; ++ct) {
    const int cbase = chunk * CHUNKN + ct * TN;
    const ushort_t* gsrc = (w < 2) ? gsrcA
        : eb + (size_t)(cbase + (lane >> 2)) * DDIM + (lane & 3) * 8;

    floatx4 acc[4][4];
    const floatx4 z4 = {0.f, 0.f, 0.f, 0.f};
#pragma unroll
    for (int i = 0; i < 4; ++i)
#pragma unroll
      for (int j = 0; j < 4; ++j) acc[i][j] = z4;

    for (int kt = 0; kt < DDIM / BK; ++kt) {
      __syncthreads();
#pragma unroll
      for (int i = 0; i < 8; ++i)
        ld2lds16(gsrc + (size_t)(i * 16) * DDIM + kt * BK, ldst + i * 512);
      __syncthreads();

      short8 ah[4], al[4], bh[4], bl[4];
#pragma unroll
      for (int i = 0; i < 4; ++i) {
        const int offA = (wm * 64 + i * 16 + col) * BK + quad * 8;
        const int offB = (wn * 64 + i * 16 + col) * BK + quad * 8;
        ah[i] = *(const short8*)&u.stg[0][offA];
        al[i] = *(const short8*)&u.stg[1][offA];
        bh[i] = *(const short8*)&u.stg[2][offB];
        bl[i] = *(const short8*)&u.stg[3][offB];
      }
#pragma unroll
      for (int i = 0; i < 4; ++i)
#pragma unroll
        for (int j = 0; j < 4; ++j) {
          acc[i][j] = mfma16(ah[i], bh[j], acc[i][j]);
          acc[i][j] = mfma16(ah[i], bl[j], acc[i][j]);
          acc[i][j] = mfma16(al[i], bh[j], acc[i][j]);
        }
    }

    int nj[4];
#pragma unroll
    for (int j = 0; j < 4; ++j) nj[j] = cbase + wn * 64 + j * 16 + col;
#pragma unroll
    for (int i = 0; i < 4; ++i)
#pragma unroll
      for (int r = 0; r < 4; ++r) {
        const int s = i * 4 + r;
#pragma unroll
        for (int j = 0; j < 4; ++j) {
          float v = acc[i][j][r];
          float mn = fminf(v, tv1[s]);
          bool gt = v > tv1[s];
          tv1[s] = gt ? v : tv1[s];
          ti1[s] = gt ? nj[j] : ti1[s];
          tv2[s] = fmaxf(tv2[s], mn);
        }
      }
  }

  __syncthreads();
  const int c = wn * 16 + col;
#pragma unroll
  for (int s = 0; s < 16; ++s) {
    const int rl = wm * 64 + (s >> 2) * 16 + quad * 4 + (s & 3);
    u.red.v1[rl][c] = tv1[s];
    u.red.v2[rl][c] = tv2[s];
    u.red.i1[rl][c] = ti1[s];
  }
  __syncthreads();
  if (t < TM) {
    float V1 = u.red.v1[t][0], V2 = u.red.v2[t][0];
    int   I1 = u.red.i1[t][0];
#pragma unroll 4
    for (int x = 1; x < 32; ++x) {
      float a1 = u.red.v1[t][x], a2 = u.red.v2[t][x];
      int   ai = u.red.i1[t][x];
      float nv2 = fmaxf(fminf(V1, a1), fmaxf(V2, a2));
      if (a1 > V1 || (a1 == V1 && ai < I1)) { V1 = a1; I1 = ai; }
      V2 = nv2;
    }
    const size_t o = (size_t)chunk * BROWS + row0 + t;
    pv1[o] = V1; pi1[o] = I1; pv2[o] = V2;
  }
}

__global__ __launch_bounds__(256) void combine_kernel(
    const float* __restrict__ pv1, const int* __restrict__ pi1,
    const float* __restrict__ pv2, int* __restrict__ idxs,
    int* __restrict__ flagcnt, int* __restrict__ flaglist) {
  const int row = blockIdx.x * 256 + threadIdx.x;
  float V1 = pv1[row], V2 = pv2[row];
  int I1 = pi1[row];
#pragma unroll
  for (int c2 = 1; c2 < NCHUNK; ++c2) {
    const size_t o = (size_t)c2 * BROWS + row;
    float a1 = pv1[o], a2 = pv2[o];
    int ai = pi1[o];
    float nv2 = fmaxf(fminf(V1, a1), fmaxf(V2, a2));
    if (a1 > V1) { V1 = a1; I1 = ai; }   // ascending chunks: tie keeps lower index
    V2 = nv2;
  }
  idxs[row] = I1;
  if (V1 - V2 < MARGIN) {
    int p = atomicAdd(flagcnt, 1);
    flaglist[p] = row;
  }
}

// Exact fp32 rerank of flagged rows. Block b owns codes [b*16, b*16+16); all blocks
// iterate all flagged rows; winner via order-preserving packed atomicMax (exact).
__global__ __launch_bounds__(256) void rerank_kernel(
    const float* __restrict__ z, const float* __restrict__ en,
    const int* __restrict__ flagcnt, const int* __restrict__ flaglist,
    unsigned long long* __restrict__ best) {
  __shared__ float sEn[16][512];
  __shared__ float sZ[512];
  const int t = threadIdx.x;
  const int cb = blockIdx.x * 16;
  for (int i = t; i < 2048; i += 256)
    ((float4*)sEn)[i] = ((const float4*)(en + (size_t)cb * DDIM))[i];
  int nf = *flagcnt;
  if (nf > BROWS) nf = BROWS;
  const int cc = t >> 4;            // code 0..15
  const int k0 = (t & 15) * 32;
  for (int f = 0; f < nf; ++f) {
    const int row = flaglist[f];
    __syncthreads();
    if (t < 128)
      ((float4*)sZ)[t] = ((const float4*)(z + (size_t)row * DDIM))[t];
    __syncthreads();
    float d = 0.0f;
    const float* zp = sZ + k0;
    const float* ep = &sEn[cc][k0];
#pragma unroll
    for (int k = 0; k < 32; ++k) d = fmaf(zp[k], ep[k], d);
    d += __shfl_xor(d, 1, 64);
    d += __shfl_xor(d, 2, 64);
    d += __shfl_xor(d, 4, 64);
    d += __shfl_xor(d, 8, 64);
    if ((t & 15) == 0) {
      uint_t ub = __float_as_uint(d);
      uint_t key = ub ^ ((uint_t)(((int)ub) >> 31) | 0x80000000u);
      unsigned long long k64 =
          ((unsigned long long)key << 32) | (uint_t)(NCODES - 1 - (cb + cc));
      atomicMax(&best[row], k64);
    }
  }
}

__global__ __launch_bounds__(256) void fixup_kernel(
    const int* __restrict__ flagcnt, const int* __restrict__ flaglist,
    const unsigned long long* __restrict__ best, int* __restrict__ idxs) {
  const int i = blockIdx.x * 256 + threadIdx.x;
  int nf = *flagcnt;
  if (nf > BROWS) nf = BROWS;
  if (i < nf) {
    const int row = flaglist[i];
    idxs[row] = NCODES - 1 - (int)(best[row] & 0xFFFFFFFFull);
  }
}

__global__ __launch_bounds__(256) void finalize_kernel(const float* __restrict__ z,
                                                       const float* __restrict__ en,
                                                       const int* __restrict__ idxs,
                                                       float* __restrict__ out_q,
                                                       float* __restrict__ out_i,
                                                       float* __restrict__ counts,
                                                       float* __restrict__ loss) {
  int w = threadIdx.x >> 6, lane = threadIdx.x & 63;
  int row = blockIdx.x * 4 + w;
  const float4* zr = (const float4*)(z + (size_t)row * DDIM);
  float4 a = zr[lane], b = zr[lane + 64];
  float s = a.x*a.x + a.y*a.y + a.z*a.z + a.w*a.w
          + b.x*b.x + b.y*b.y + b.z*b.z + b.w*b.w;
  s = wave_sum(s);
  float inv = 1.0f / fmaxf(sqrtf(s), 1e-12f);
  int k = idxs[row];
  const float4* qr = (const float4*)(en + (size_t)k * DDIM);
  float4 qa = qr[lane], qb = qr[lane + 64];
  float d = 0.0f;
  float4 oa, ob;
  {
    float zn;
    zn = a.x * inv; oa.x = zn + (qa.x - zn); d += (zn - qa.x) * (zn - qa.x);
    zn = a.y * inv; oa.y = zn + (qa.y - zn); d += (zn - qa.y) * (zn - qa.y);
    zn = a.z * inv; oa.z = zn + (qa.z - zn); d += (zn - qa.z) * (zn - qa.z);
    zn = a.w * inv; oa.w = zn + (qa.w - zn); d += (zn - qa.w) * (zn - qa.w);
    zn = b.x * inv; ob.x = zn + (qb.x - zn); d += (zn - qb.x) * (zn - qb.x);
    zn = b.y * inv; ob.y = zn + (qb.y - zn); d += (zn - qb.y) * (zn - qb.y);
    zn = b.z * inv; ob.z = zn + (qb.z - zn); d += (zn - qb.z) * (zn - qb.z);
    zn = b.w * inv; ob.w = zn + (qb.w - zn); d += (zn - qb.w) * (zn - qb.w);
  }
  float4* orow = (float4*)(out_q + (size_t)row * DDIM);
  orow[lane] = oa;
  orow[lane + 64] = ob;
  d = wave_sum(d);
  if (lane == 0) {
    atomicAdd(loss, d);
    atomicAdd(&counts[k], 1.0f);
    out_i[row] = (float)k;
  }
}

__global__ __launch_bounds__(256) void scalars_kernel(const float* __restrict__ counts,
                                                      const float* __restrict__ loss,
                                                      float* __restrict__ o) {
  __shared__ float se[256], su[256];
  int t = threadIdx.x;
  float ent = 0.0f, utl = 0.0f;
  for (int i = t; i < NCODES; i += 256) {
    float c = counts[i];
    float p = c * (1.0f / (float)BROWS);
    ent -= p * logf(p + 1e-10f);
    utl += (c > 0.0f) ? 1.0f : 0.0f;
  }
  se[t] = ent; su[t] = utl;
  __syncthreads();
  for (int s2 = 128; s2 > 0; s2 >>= 1) {
    if (t < s2) { se[t] += se[t + s2]; su[t] += su[t + s2]; }
    __syncthreads();
  }
  if (t == 0) {
    float mse = (*loss) * (1.0f / (float)(BROWS * DDIM));
    o[0] = 0.25f * mse;
    o[1] = mse;
    o[2] = expf(se[0]);
    o[3] = su[0] * (1.0f / (float)NCODES);
  }
}

// ---------- fallback (R1 fp32 path, used only if ws too small) ----------
__global__ __launch_bounds__(256) void fb_norm_rows(const float* __restrict__ e,
                                                    float* __restrict__ en) {
  int w = threadIdx.x >> 6, lane = threadIdx.x & 63;
  int row = blockIdx.x * 4 + w;
  const float4* src = (const float4*)(e + (size_t)row * DDIM);
  float4 a = src[lane], b = src[lane + 64];
  float s = a.x*a.x + a.y*a.y + a.z*a.z + a.w*a.w
          + b.x*b.x + b.y*b.y + b.z*b.z + b.w*b.w;
  s = wave_sum(s);
  float inv = 1.0f / fmaxf(sqrtf(s), 1e-12f);
  float4* dst = (float4*)(en + (size_t)row * DDIM);
  dst[lane] = make_float4(a.x*inv, a.y*inv, a.z*inv, a.w*inv);
  dst[lane + 64] = make_float4(b.x*inv, b.y*inv, b.z*inv, b.w*inv);
}

__global__ __launch_bounds__(256) void fb_gemm_argmax(const float* __restrict__ z,
                                                      const float* __restrict__ en,
                                                      int* __restrict__ out_idx) {
  __shared__ float As[16][TM + 4];
  __shared__ float Bs[16][TN + 4];
  __shared__ float rv[TM][16];
  __shared__ int   ri[TM][16];
  const int t = threadIdx.x;
  const int tx = t & 15, ty = t >> 4;
  const int row0 = blockIdx.x * TM;
  const int m = t >> 2, f4 = t & 3;
  float bestv[8]; int bestn[8];
#pragma unroll
  for (int i = 0; i < 8; ++i) { bestv[i] = -3.0e38f; bestn[i] = 0; }
  for (int ct = 0; ct < NCODES / TN; ++ct) {
    float acc[8][8];
#pragma unroll
    for (int i = 0; i < 8; ++i)
#pragma unroll
      for (int j = 0; j < 8; ++j) acc[i][j] = 0.0f;
    for (int kt = 0; kt < DDIM / 16; ++kt) {
      const int k0 = kt * 16;
      __syncthreads();
      {
        const float* zb = z + (size_t)(row0 + m) * DDIM + k0 + f4 * 4;
        float4 v0 = *(const float4*)zb;
        float4 v1 = *(const float4*)(zb + (size_t)64 * DDIM);
        const float* ebp = en + (size_t)(ct * TN + m) * DDIM + k0 + f4 * 4;
        float4 w0 = *(const float4*)ebp;
        float4 w1 = *(const float4*)(ebp + (size_t)64 * DDIM);
        const int kk = f4 * 4;
        As[kk+0][m] = v0.x; As[kk+1][m] = v0.y; As[kk+2][m] = v0.z; As[kk+3][m] = v0.w;
        As[kk+0][m+64] = v1.x; As[kk+1][m+64] = v1.y; As[kk+2][m+64] = v1.z; As[kk+3][m+64] = v1.w;
        Bs[kk+0][m] = w0.x; Bs[kk+1][m] = w0.y; Bs[kk+2][m] = w0.z; Bs[kk+3][m] = w0.w;
        Bs[kk+0][m+64] = w1.x; Bs[kk+1][m+64] = w1.y; Bs[kk+2][m+64] = w1.z; Bs[kk+3][m+64] = w1.w;
      }
      __syncthreads();
#pragma unroll
      for (int k = 0; k < 16; ++k) {
        float4 a0 = *(const float4*)&As[k][ty * 8];
        float4 a1 = *(const float4*)&As[k][ty * 8 + 4];
        float4 b0 = *(const float4*)&Bs[k][tx * 4];
        float4 b1 = *(const float4*)&Bs[k][64 + tx * 4];
        float a[8] = {a0.x,a0.y,a0.z,a0.w,a1.x,a1.y,a1.z,a1.w};
        float b[8] = {b0.x,b0.y,b0.z,b0.w,b1.x,b1.y,b1.z,b1.w};
#pragma unroll
        for (int i = 0; i < 8; ++i)
#pragma unroll
          for (int j = 0; j < 8; ++j) acc[i][j] = fmaf(a[i], b[j], acc[i][j]);
      }
    }
    const int nb = ct * TN;
#pragma unroll
    for (int i = 0; i < 8; ++i)
#pragma unroll
      for (int j = 0; j < 8; ++j) {
        int n = nb + ((j < 4) ? (tx * 4 + j) : (64 + tx * 4 + (j - 4)));
        if (acc[i][j] > bestv[i]) { bestv[i] = acc[i][j]; bestn[i] = n; }
      }
  }
#pragma unroll
  for (int i = 0; i < 8; ++i) { rv[ty*8+i][tx] = bestv[i]; ri[ty*8+i][tx] = bestn[i]; }
  __syncthreads();
  if (t < TM) {
    float bv = rv[t][0]; int bi = ri[t][0];
#pragma unroll
    for (int x = 1; x < 16; ++x) {
      float v = rv[t][x]; int n = ri[t][x];
      if (v > bv || (v == bv && n < bi)) { bv = v; bi = n; }
    }
    out_idx[row0 + t] = bi;
  }
}

extern "C" void kernel_launch(void* const* d_in, const int* in_sizes, int n_in,
                              void* d_out, int out_size, void* d_ws, size_t ws_size,
                              hipStream_t stream) {
  const float* z = (const float*)d_in[0];
  const float* e = (const float*)d_in[1];
  float* out = (float*)d_out;
  float* ws = (float*)d_ws;

  float* out_q = out;
  float* out_i = out + (size_t)BROWS * DDIM;
  float* out_s = out_i + BROWS;

  const size_t ENF = (size_t)NCODES * DDIM;   // 4,194,304
  const size_t ZNF = (size_t)BROWS * DDIM;    // 16,777,216

  // fast-path ws layout (float-unit offsets)
  size_t off = 0;
  float*    en      = ws + off;              off += ENF;
  ushort_t* enh     = (ushort_t*)(ws + off); off += ENF / 2;
  ushort_t* enl     = (ushort_t*)(ws + off); off += ENF / 2;
  ushort_t* zh      = (ushort_t*)(ws + off); off += ZNF / 2;
  ushort_t* zl      = (ushort_t*)(ws + off); off += ZNF / 2;
  unsigned long long* best = (unsigned long long*)(ws + off); off += (size_t)BROWS * 2;
  float*    pv1     = ws + off;              off += (size_t)NCHUNK * BROWS;
  int*      pi1     = (int*)(ws + off);      off += (size_t)NCHUNK * BROWS;
  float*    pv2     = ws + off;              off += (size_t)NCHUNK * BROWS;
  int*      idxs    = (int*)(ws + off);      off += BROWS;
  int*      flaglist= (int*)(ws + off);      off += BROWS;
  float*    counts  = ws + off;              off += NCODES;
  float*    loss    = ws + off;              off += 1;
  int*      flagcnt = (int*)(ws + off);      off += 1;
  const size_t need_bytes = off * sizeof(float);

  if (ws_size >= need_bytes) {
    prep_split_kernel<<<NCODES / 4, 256, 0, stream>>>(e, en, enh, enl);
    prep_split_kernel<<<BROWS / 4, 256, 0, stream>>>(z, nullptr, zh, zl);
    hipMemsetAsync(counts, 0, (NCODES + 2) * sizeof(float), stream);
    hipMemsetAsync(best, 0, (size_t)BROWS * sizeof(unsigned long long), stream);
    dim3 g(NCHUNK, BROWS / TM);
    gemm3_kernel<<<g, 256, 0, stream>>>(zh, zl, enh, enl, pv1, pi1, pv2);
    combine_kernel<<<BROWS / 256, 256, 0, stream>>>(pv1, pi1, pv2, idxs, flagcnt, flaglist);
    rerank_kernel<<<NCODES / 16, 256, 0, stream>>>(z, en, flagcnt, flaglist, best);
    fixup_kernel<<<BROWS / 256, 256, 0, stream>>>(flagcnt, flaglist, best, idxs);
    finalize_kernel<<<BROWS / 4, 256, 0, stream>>>(z, en, idxs, out_q, out_i, counts, loss);
    scalars_kernel<<<1, 256, 0, stream>>>(counts, loss, out_s);
  } else {
    // fallback: R1 fp32 path (~17 MB ws)
    float* fen    = ws;
    int*   fidx   = (int*)(fen + ENF);
    float* fcnt   = (float*)(fidx + BROWS);
    float* floss  = fcnt + NCODES;
    fb_norm_rows<<<NCODES / 4, 256, 0, stream>>>(e, fen);
    hipMemsetAsync(fcnt, 0, (NCODES + 1) * sizeof(float), stream);
    fb_gemm_argmax<<<BROWS / TM, 256, 0, stream>>>(z, fen, fidx);
    finalize_kernel<<<BROWS / 4, 256, 0, stream>>>(z, fen, fidx, out_q, out_i, fcnt, floss);
    scalars_kernel<<<1, 256, 0, stream>>>(fcnt, floss, out_s);
  }
}

// Round 3
// 2372.540 us; speedup vs baseline: 1.8924x; 1.1591x over previous
//
#include <hip/hip_runtime.h>

#define BROWS  32768
#define DDIM   512
#define NCODES 8192
#define NCHUNK 4
#define CHUNKN (NCODES / NCHUNK)   // 2048
#define TM     128
#define TN     128
#define BK     32
#define MARGIN 2e-5f

typedef unsigned short ushort_t;
typedef unsigned int   uint_t;
typedef __attribute__((ext_vector_type(8))) short  short8;
typedef __attribute__((ext_vector_type(4))) float  floatx4;

__device__ __forceinline__ float wave_sum(float v) {
#pragma unroll
  for (int o = 32; o > 0; o >>= 1) v += __shfl_xor(v, o, 64);
  return v;
}

__device__ __forceinline__ floatx4 mfma16(short8 a, short8 b, floatx4 c) {
  return __builtin_amdgcn_mfma_f32_16x16x32_bf16(a, b, c, 0, 0, 0);
}

// async global->LDS, 16B per lane; lds dst is wave-uniform base + lane*16 (HW rule)
__device__ __forceinline__ void ld2lds16(const ushort_t* g, ushort_t* l) {
  __builtin_amdgcn_global_load_lds((__attribute__((address_space(1))) void*)g,
                                   (__attribute__((address_space(3))) void*)l,
                                   16, 0, 0);
}

__device__ __forceinline__ void split1(float v, ushort_t& h, ushort_t& l) {
  uint_t u  = __float_as_uint(v);
  uint_t hb = (u + 0x7FFFu + ((u >> 16) & 1u)) >> 16;   // RNE
  h = (ushort_t)hb;
  float r = v - __uint_as_float(hb << 16);               // exact (Sterbenz)
  uint_t u2 = __float_as_uint(r);
  l = (ushort_t)((u2 + 0x7FFFu + ((u2 >> 16) & 1u)) >> 16);
}

// Normalize rows of x (4 rows/block, wave per row); write fp32 (optional) + bf16 hi/lo.
__global__ __launch_bounds__(256) void prep_split_kernel(const float* __restrict__ x,
                                                         float* __restrict__ xn,
                                                         ushort_t* __restrict__ xh,
                                                         ushort_t* __restrict__ xl) {
  const int w = threadIdx.x >> 6, lane = threadIdx.x & 63;
  const size_t row = (size_t)blockIdx.x * 4 + w;
  const float4* src = (const float4*)(x + row * DDIM);
  float4 a = src[lane], b = src[lane + 64];
  float s = a.x*a.x + a.y*a.y + a.z*a.z + a.w*a.w
          + b.x*b.x + b.y*b.y + b.z*b.z + b.w*b.w;
  s = wave_sum(s);
  const float inv = 1.0f / fmaxf(sqrtf(s), 1e-12f);
  a.x *= inv; a.y *= inv; a.z *= inv; a.w *= inv;
  b.x *= inv; b.y *= inv; b.z *= inv; b.w *= inv;
  if (xn) {
    float4* dst = (float4*)(xn + row * DDIM);
    dst[lane] = a; dst[lane + 64] = b;
  }
  ushort4 h0, l0, h1, l1;
  split1(a.x, h0.x, l0.x); split1(a.y, h0.y, l0.y);
  split1(a.z, h0.z, l0.z); split1(a.w, h0.w, l0.w);
  split1(b.x, h1.x, l1.x); split1(b.y, h1.y, l1.y);
  split1(b.z, h1.z, l1.z); split1(b.w, h1.w, l1.w);
  ushort4* ph = (ushort4*)(xh + row * DDIM);
  ushort4* pl = (ushort4*)(xl + row * DDIM);
  ph[lane] = h0; ph[lane + 64] = h1;
  pl[lane] = l0; pl[lane + 64] = l1;
}

// bf16x2 (3-MFMA) GEMM over one N-chunk, tracking per-row top1 (v,i) + top2 (v).
// LDS layout XOR-swizzled: chunk c of row r lives at r*64B + (c ^ ((r>>1)&3))*16B
// -> ds_read_b128 fragment reads are bank-conflict-free; staging writes stay
// contiguous 1KB per global_load_lds.
__global__ __launch_bounds__(256, 2) void gemm3_kernel(
    const ushort_t* __restrict__ zh, const ushort_t* __restrict__ zl,
    const ushort_t* __restrict__ eh, const ushort_t* __restrict__ el,
    float* __restrict__ pv1, int* __restrict__ pi1, float* __restrict__ pv2) {
  __shared__ union {
    ushort_t stg[4][TM * BK];                            // Ah Al Bh Bl : 4 x 8 KB
    struct { float v1[TM][2]; float v2[TM][2]; int i1[TM][2]; } red;  // 3 KB
  } u;
  const int t = threadIdx.x;
  const int w = t >> 6;            // wave 0..3
  const int lane = t & 63;
  const int wm = w >> 1, wn = w & 1;
  const int col = lane & 15;
  const int quad = lane >> 4;
  const int chunk = blockIdx.x;
  const int row0 = blockIdx.y * TM;

  // staging source: lane l -> row (l>>2), swizzled chunk (l&3)^((l>>3)&3)
  const int swc = ((lane & 3) ^ ((lane >> 3) & 3)) * 8;  // ushort offset of 16B chunk
  const ushort_t* gsrcA = (w == 0 ? zh : zl)
      + (size_t)(row0 + (lane >> 2)) * DDIM + swc;
  const ushort_t* eb = (w == 2) ? eh : el;
  ushort_t* ldst = u.stg[w];

  // fragment-read swizzle (row parity bits): (quad ^ ((col>>1)&3)) * 8 ushorts
  const int swr = (quad ^ ((col >> 1) & 3)) * 8;

  float tv1[16], tv2[16]; int ti1[16];
#pragma unroll
  for (int s = 0; s < 16; ++s) { tv1[s] = -3.0e38f; tv2[s] = -3.0e38f; ti1[s] = 0; }

  for (int ct = 0; ct < CHUNKN / TN; ++ct) {
    const int cbase = chunk * CHUNKN + ct * TN;
    const ushort_t* gsrc = (w < 2) ? gsrcA
        : eb + (size_t)(cbase + (lane >> 2)) * DDIM + swc;

    floatx4 acc[4][4];
    const floatx4 z4 = {0.f, 0.f, 0.f, 0.f};
#pragma unroll
    for (int i = 0; i < 4; ++i)
#pragma unroll
      for (int j = 0; j < 4; ++j) acc[i][j] = z4;

    for (int kt = 0; kt < DDIM / BK; ++kt) {
      __syncthreads();
#pragma unroll
      for (int i = 0; i < 8; ++i)
        ld2lds16(gsrc + (size_t)(i * 16) * DDIM + kt * BK, ldst + i * 512);
      __syncthreads();

      short8 ah[4], al[4], bh[4], bl[4];
#pragma unroll
      for (int i = 0; i < 4; ++i) {
        const int offA = (wm * 64 + i * 16 + col) * BK + swr;
        const int offB = (wn * 64 + i * 16 + col) * BK + swr;
        ah[i] = *(const short8*)&u.stg[0][offA];
        al[i] = *(const short8*)&u.stg[1][offA];
        bh[i] = *(const short8*)&u.stg[2][offB];
        bl[i] = *(const short8*)&u.stg[3][offB];
      }
#pragma unroll
      for (int i = 0; i < 4; ++i)
#pragma unroll
        for (int j = 0; j < 4; ++j) {
          acc[i][j] = mfma16(ah[i], bh[j], acc[i][j]);
          acc[i][j] = mfma16(ah[i], bl[j], acc[i][j]);
          acc[i][j] = mfma16(al[i], bh[j], acc[i][j]);
        }
    }

    int nj[4];
#pragma unroll
    for (int j = 0; j < 4; ++j) nj[j] = cbase + wn * 64 + j * 16 + col;
#pragma unroll
    for (int i = 0; i < 4; ++i)
#pragma unroll
      for (int r = 0; r < 4; ++r) {
        const int s = i * 4 + r;
#pragma unroll
        for (int j = 0; j < 4; ++j) {
          float v = acc[i][j][r];
          float mn = fminf(v, tv1[s]);
          bool gt = v > tv1[s];
          tv1[s] = gt ? v : tv1[s];
          ti1[s] = gt ? nj[j] : ti1[s];
          tv2[s] = fmaxf(tv2[s], mn);
        }
      }
  }

  // intra-wave top-2 reduce across the 16 col-lanes (lane bits 0..3)
#pragma unroll
  for (int off = 1; off < 16; off <<= 1) {
#pragma unroll
    for (int s = 0; s < 16; ++s) {
      float ov1 = __shfl_xor(tv1[s], off, 64);
      int   oi1 = __shfl_xor(ti1[s], off, 64);
      float ov2 = __shfl_xor(tv2[s], off, 64);
      float nv2 = fmaxf(fminf(tv1[s], ov1), fmaxf(tv2[s], ov2));
      if (ov1 > tv1[s] || (ov1 == tv1[s] && oi1 < ti1[s])) { tv1[s] = ov1; ti1[s] = oi1; }
      tv2[s] = nv2;
    }
  }
  __syncthreads();   // staging LDS reuse as reduction scratch
  if (col == 0) {
#pragma unroll
    for (int s = 0; s < 16; ++s) {
      const int rl = wm * 64 + (s >> 2) * 16 + quad * 4 + (s & 3);
      u.red.v1[rl][wn] = tv1[s];
      u.red.v2[rl][wn] = tv2[s];
      u.red.i1[rl][wn] = ti1[s];
    }
  }
  __syncthreads();
  if (t < TM) {
    float V1 = u.red.v1[t][0], V2 = u.red.v2[t][0];
    int   I1 = u.red.i1[t][0];
    float a1 = u.red.v1[t][1], a2 = u.red.v2[t][1];
    int   ai = u.red.i1[t][1];
    float nv2 = fmaxf(fminf(V1, a1), fmaxf(V2, a2));
    if (a1 > V1 || (a1 == V1 && ai < I1)) { V1 = a1; I1 = ai; }
    V2 = nv2;
    const size_t o = (size_t)chunk * BROWS + row0 + t;
    pv1[o] = V1; pi1[o] = I1; pv2[o] = V2;
  }
}

__global__ __launch_bounds__(256) void combine_kernel(
    const float* __restrict__ pv1, const int* __restrict__ pi1,
    const float* __restrict__ pv2, int* __restrict__ idxs,
    int* __restrict__ flagcnt, int* __restrict__ flaglist) {
  const int row = blockIdx.x * 256 + threadIdx.x;
  float V1 = pv1[row], V2 = pv2[row];
  int I1 = pi1[row];
#pragma unroll
  for (int c2 = 1; c2 < NCHUNK; ++c2) {
    const size_t o = (size_t)c2 * BROWS + row;
    float a1 = pv1[o], a2 = pv2[o];
    int ai = pi1[o];
    float nv2 = fmaxf(fminf(V1, a1), fmaxf(V2, a2));
    if (a1 > V1) { V1 = a1; I1 = ai; }   // ascending chunks: tie keeps lower index
    V2 = nv2;
  }
  idxs[row] = I1;
  if (V1 - V2 < MARGIN) {
    int p = atomicAdd(flagcnt, 1);
    flaglist[p] = row;
  }
}

// Exact fp32 rerank: one block per flagged row (strided), full 8192-code scan,
// block-local argmax with first-index tie-break, direct idxs write.
__global__ __launch_bounds__(256) void rerank_kernel(
    const float* __restrict__ z, const float* __restrict__ en,
    const int* __restrict__ flagcnt, const int* __restrict__ flaglist,
    int* __restrict__ idxs) {
  __shared__ float sZ[512];
  __shared__ float sv[256];
  __shared__ int   si[256];
  const int t = threadIdx.x;
  int nf = *flagcnt;
  if (nf > BROWS) nf = BROWS;
  for (int f = blockIdx.x; f < nf; f += gridDim.x) {
    const int row = flaglist[f];
    __syncthreads();
    if (t < 128) ((float4*)sZ)[t] = ((const float4*)(z + (size_t)row * DDIM))[t];
    __syncthreads();
    float bv = -3.0e38f; int bi = 0;
    for (int c = t; c < NCODES; c += 256) {
      const float4* ep = (const float4*)(en + (size_t)c * DDIM);
      float d = 0.0f;
#pragma unroll 16
      for (int k4 = 0; k4 < 128; ++k4) {
        float4 e4 = ep[k4];
        float4 zv = ((const float4*)sZ)[k4];
        d = fmaf(e4.x, zv.x, d); d = fmaf(e4.y, zv.y, d);
        d = fmaf(e4.z, zv.z, d); d = fmaf(e4.w, zv.w, d);
      }
      if (d > bv) { bv = d; bi = c; }   // ascending c: tie keeps lower index
    }
    sv[t] = bv; si[t] = bi;
    __syncthreads();
    for (int s2 = 128; s2 > 0; s2 >>= 1) {
      if (t < s2) {
        float ov = sv[t + s2]; int oi = si[t + s2];
        if (ov > sv[t] || (ov == sv[t] && oi < si[t])) { sv[t] = ov; si[t] = oi; }
      }
      __syncthreads();
    }
    if (t == 0) idxs[row] = si[0];
    __syncthreads();
  }
}

__global__ __launch_bounds__(256) void finalize_kernel(const float* __restrict__ z,
                                                       const float* __restrict__ en,
                                                       const int* __restrict__ idxs,
                                                       float* __restrict__ out_q,
                                                       float* __restrict__ out_i,
                                                       float* __restrict__ counts,
                                                       float* __restrict__ loss) {
  int w = threadIdx.x >> 6, lane = threadIdx.x & 63;
  int row = blockIdx.x * 4 + w;
  const float4* zr = (const float4*)(z + (size_t)row * DDIM);
  float4 a = zr[lane], b = zr[lane + 64];
  float s = a.x*a.x + a.y*a.y + a.z*a.z + a.w*a.w
          + b.x*b.x + b.y*b.y + b.z*b.z + b.w*b.w;
  s = wave_sum(s);
  float inv = 1.0f / fmaxf(sqrtf(s), 1e-12f);
  int k = idxs[row];
  const float4* qr = (const float4*)(en + (size_t)k * DDIM);
  float4 qa = qr[lane], qb = qr[lane + 64];
  float d = 0.0f;
  float4 oa, ob;
  {
    float zn;
    zn = a.x * inv; oa.x = zn + (qa.x - zn); d += (zn - qa.x) * (zn - qa.x);
    zn = a.y * inv; oa.y = zn + (qa.y - zn); d += (zn - qa.y) * (zn - qa.y);
    zn = a.z * inv; oa.z = zn + (qa.z - zn); d += (zn - qa.z) * (zn - qa.z);
    zn = a.w * inv; oa.w = zn + (qa.w - zn); d += (zn - qa.w) * (zn - qa.w);
    zn = b.x * inv; ob.x = zn + (qb.x - zn); d += (zn - qb.x) * (zn - qb.x);
    zn = b.y * inv; ob.y = zn + (qb.y - zn); d += (zn - qb.y) * (zn - qb.y);
    zn = b.z * inv; ob.z = zn + (qb.z - zn); d += (zn - qb.z) * (zn - qb.z);
    zn = b.w * inv; ob.w = zn + (qb.w - zn); d += (zn - qb.w) * (zn - qb.w);
  }
  float4* orow = (float4*)(out_q + (size_t)row * DDIM);
  orow[lane] = oa;
  orow[lane + 64] = ob;
  d = wave_sum(d);
  if (lane == 0) {
    atomicAdd(loss, d);
    atomicAdd(&counts[k], 1.0f);
    out_i[row] = (float)k;
  }
}

__global__ __launch_bounds__(256) void scalars_kernel(const float* __restrict__ counts,
                                                      const float* __restrict__ loss,
                                                      float* __restrict__ o) {
  __shared__ float se[256], su[256];
  int t = threadIdx.x;
  float ent = 0.0f, utl = 0.0f;
  for (int i = t; i < NCODES; i += 256) {
    float c = counts[i];
    float p = c * (1.0f / (float)BROWS);
    ent -= p * logf(p + 1e-10f);
    utl += (c > 0.0f) ? 1.0f : 0.0f;
  }
  se[t] = ent; su[t] = utl;
  __syncthreads();
  for (int s2 = 128; s2 > 0; s2 >>= 1) {
    if (t < s2) { se[t] += se[t + s2]; su[t] += su[t + s2]; }
    __syncthreads();
  }
  if (t == 0) {
    float mse = (*loss) * (1.0f / (float)(BROWS * DDIM));
    o[0] = 0.25f * mse;
    o[1] = mse;
    o[2] = expf(se[0]);
    o[3] = su[0] * (1.0f / (float)NCODES);
  }
}

// ---------- fallback (R1 fp32 path, used only if ws too small) ----------
__global__ __launch_bounds__(256) void fb_norm_rows(const float* __restrict__ e,
                                                    float* __restrict__ en) {
  int w = threadIdx.x >> 6, lane = threadIdx.x & 63;
  int row = blockIdx.x * 4 + w;
  const float4* src = (const float4*)(e + (size_t)row * DDIM);
  float4 a = src[lane], b = src[lane + 64];
  float s = a.x*a.x + a.y*a.y + a.z*a.z + a.w*a.w
          + b.x*b.x + b.y*b.y + b.z*b.z + b.w*b.w;
  s = wave_sum(s);
  float inv = 1.0f / fmaxf(sqrtf(s), 1e-12f);
  float4* dst = (float4*)(en + (size_t)row * DDIM);
  dst[lane] = make_float4(a.x*inv, a.y*inv, a.z*inv, a.w*inv);
  dst[lane + 64] = make_float4(b.x*inv, b.y*inv, b.z*inv, b.w*inv);
}

__global__ __launch_bounds__(256) void fb_gemm_argmax(const float* __restrict__ z,
                                                      const float* __restrict__ en,
                                                      int* __restrict__ out_idx) {
  __shared__ float As[16][TM + 4];
  __shared__ float Bs[16][TN + 4];
  __shared__ float rv[TM][16];
  __shared__ int   ri[TM][16];
  const int t = threadIdx.x;
  const int tx = t & 15, ty = t >> 4;
  const int row0 = blockIdx.x * TM;
  const int m = t >> 2, f4 = t & 3;
  float bestv[8]; int bestn[8];
#pragma unroll
  for (int i = 0; i < 8; ++i) { bestv[i] = -3.0e38f; bestn[i] = 0; }
  for (int ct = 0; ct < NCODES / TN; ++ct) {
    float acc[8][8];
#pragma unroll
    for (int i = 0; i < 8; ++i)
#pragma unroll
      for (int j = 0; j < 8; ++j) acc[i][j] = 0.0f;
    for (int kt = 0; kt < DDIM / 16; ++kt) {
      const int k0 = kt * 16;
      __syncthreads();
      {
        const float* zb = z + (size_t)(row0 + m) * DDIM + k0 + f4 * 4;
        float4 v0 = *(const float4*)zb;
        float4 v1 = *(const float4*)(zb + (size_t)64 * DDIM);
        const float* ebp = en + (size_t)(ct * TN + m) * DDIM + k0 + f4 * 4;
        float4 w0 = *(const float4*)ebp;
        float4 w1 = *(const float4*)(ebp + (size_t)64 * DDIM);
        const int kk = f4 * 4;
        As[kk+0][m] = v0.x; As[kk+1][m] = v0.y; As[kk+2][m] = v0.z; As[kk+3][m] = v0.w;
        As[kk+0][m+64] = v1.x; As[kk+1][m+64] = v1.y; As[kk+2][m+64] = v1.z; As[kk+3][m+64] = v1.w;
        Bs[kk+0][m] = w0.x; Bs[kk+1][m] = w0.y; Bs[kk+2][m] = w0.z; Bs[kk+3][m] = w0.w;
        Bs[kk+0][m+64] = w1.x; Bs[kk+1][m+64] = w1.y; Bs[kk+2][m+64] = w1.z; Bs[kk+3][m+64] = w1.w;
      }
      __syncthreads();
#pragma unroll
      for (int k = 0; k < 16; ++k) {
        float4 a0 = *(const float4*)&As[k][ty * 8];
        float4 a1 = *(const float4*)&As[k][ty * 8 + 4];
        float4 b0 = *(const float4*)&Bs[k][tx * 4];
        float4 b1 = *(const float4*)&Bs[k][64 + tx * 4];
        float a[8] = {a0.x,a0.y,a0.z,a0.w,a1.x,a1.y,a1.z,a1.w};
        float b[8] = {b0.x,b0.y,b0.z,b0.w,b1.x,b1.y,b1.z,b1.w};
#pragma unroll
        for (int i = 0; i < 8; ++i)
#pragma unroll
          for (int j = 0; j < 8; ++j) acc[i][j] = fmaf(a[i], b[j], acc[i][j]);
      }
    }
    const int nb = ct * TN;
#pragma unroll
    for (int i = 0; i < 8; ++i)
#pragma unroll
      for (int j = 0; j < 8; ++j) {
        int n = nb + ((j < 4) ? (tx * 4 + j) : (64 + tx * 4 + (j - 4)));
        if (acc[i][j] > bestv[i]) { bestv[i] = acc[i][j]; bestn[i] = n; }
      }
  }
#pragma unroll
  for (int i = 0; i < 8; ++i) { rv[ty*8+i][tx] = bestv[i]; ri[ty*8+i][tx] = bestn[i]; }
  __syncthreads();
  if (t < TM) {
    float bv = rv[t][0]; int bi = ri[t][0];
#pragma unroll
    for (int x = 1; x < 16; ++x) {
      float v = rv[t][x]; int n = ri[t][x];
      if (v > bv || (v == bv && n < bi)) { bv = v; bi = n; }
    }
    out_idx[row0 + t] = bi;
  }
}

extern "C" void kernel_launch(void* const* d_in, const int* in_sizes, int n_in,
                              void* d_out, int out_size, void* d_ws, size_t ws_size,
                              hipStream_t stream) {
  const float* z = (const float*)d_in[0];
  const float* e = (const float*)d_in[1];
  float* out = (float*)d_out;
  float* ws = (float*)d_ws;

  float* out_q = out;
  float* out_i = out + (size_t)BROWS * DDIM;
  float* out_s = out_i + BROWS;

  const size_t ENF = (size_t)NCODES * DDIM;   // 4,194,304
  const size_t ZNF = (size_t)BROWS * DDIM;    // 16,777,216

  // fast-path ws layout (float-unit offsets)
  size_t off = 0;
  float*    en      = ws + off;              off += ENF;
  ushort_t* enh     = (ushort_t*)(ws + off); off += ENF / 2;
  ushort_t* enl     = (ushort_t*)(ws + off); off += ENF / 2;
  ushort_t* zh      = (ushort_t*)(ws + off); off += ZNF / 2;
  ushort_t* zl      = (ushort_t*)(ws + off); off += ZNF / 2;
  float*    pv1     = ws + off;              off += (size_t)NCHUNK * BROWS;
  int*      pi1     = (int*)(ws + off);      off += (size_t)NCHUNK * BROWS;
  float*    pv2     = ws + off;              off += (size_t)NCHUNK * BROWS;
  int*      idxs    = (int*)(ws + off);      off += BROWS;
  int*      flaglist= (int*)(ws + off);      off += BROWS;
  float*    counts  = ws + off;              off += NCODES;
  float*    loss    = ws + off;              off += 1;
  int*      flagcnt = (int*)(ws + off);      off += 1;
  const size_t need_bytes = off * sizeof(float);

  if (ws_size >= need_bytes) {
    prep_split_kernel<<<NCODES / 4, 256, 0, stream>>>(e, en, enh, enl);
    prep_split_kernel<<<BROWS / 4, 256, 0, stream>>>(z, nullptr, zh, zl);
    hipMemsetAsync(counts, 0, (NCODES + 2) * sizeof(float), stream);
    dim3 g(NCHUNK, BROWS / TM);
    gemm3_kernel<<<g, 256, 0, stream>>>(zh, zl, enh, enl, pv1, pi1, pv2);
    combine_kernel<<<BROWS / 256, 256, 0, stream>>>(pv1, pi1, pv2, idxs, flagcnt, flaglist);
    rerank_kernel<<<256, 256, 0, stream>>>(z, en, flagcnt, flaglist, idxs);
    finalize_kernel<<<BROWS / 4, 256, 0, stream>>>(z, en, idxs, out_q, out_i, counts, loss);
    scalars_kernel<<<1, 256, 0, stream>>>(counts, loss, out_s);
  } else {
    // fallback: R1 fp32 path (~17 MB ws)
    float* fen    = ws;
    int*   fidx   = (int*)(fen + ENF);
    float* fcnt   = (float*)(fidx + BROWS);
    float* floss  = fcnt + NCODES;
    fb_norm_rows<<<NCODES / 4, 256, 0, stream>>>(e, fen);
    hipMemsetAsync(fcnt, 0, (NCODES + 1) * sizeof(float), stream);
    fb_gemm_argmax<<<BROWS / TM, 256, 0, stream>>>(z, fen, fidx);
    finalize_kernel<<<BROWS / 4, 256, 0, stream>>>(z, fen, fidx, out_q, out_i, fcnt, floss);
    scalars_kernel<<<1, 256, 0, stream>>>(fcnt, floss, out_s);
  }
}

// Round 4
// 1999.627 us; speedup vs baseline: 2.2453x; 1.1865x over previous
//
#include <hip/hip_runtime.h>

#define BROWS  32768
#define DDIM   512
#define NCODES 8192
#define NCHUNK 4
#define CHUNKN (NCODES / NCHUNK)   // 2048
#define TM     128
#define TN     128
#define BK     32
#define MARGIN 6e-6f

typedef unsigned short ushort_t;
typedef unsigned int   uint_t;
typedef __attribute__((ext_vector_type(8))) short  short8;
typedef __attribute__((ext_vector_type(4))) short  short4v;
typedef __attribute__((ext_vector_type(4))) float  floatx4;

__device__ __forceinline__ float wave_sum(float v) {
#pragma unroll
  for (int o = 32; o > 0; o >>= 1) v += __shfl_xor(v, o, 64);
  return v;
}

__device__ __forceinline__ floatx4 mfma16(short8 a, short8 b, floatx4 c) {
  return __builtin_amdgcn_mfma_f32_16x16x32_bf16(a, b, c, 0, 0, 0);
}

// async global->LDS, 16B per lane; lds dst is wave-uniform base + lane*16 (HW rule)
__device__ __forceinline__ void ld2lds16(const ushort_t* g, ushort_t* l) {
  __builtin_amdgcn_global_load_lds((__attribute__((address_space(1))) void*)g,
                                   (__attribute__((address_space(3))) void*)l,
                                   16, 0, 0);
}

__device__ __forceinline__ void split1(float v, ushort_t& h, ushort_t& l) {
  uint_t u  = __float_as_uint(v);
  uint_t hb = (u + 0x7FFFu + ((u >> 16) & 1u)) >> 16;   // RNE
  h = (ushort_t)hb;
  float r = v - __uint_as_float(hb << 16);               // exact (Sterbenz)
  uint_t u2 = __float_as_uint(r);
  l = (ushort_t)((u2 + 0x7FFFu + ((u2 >> 16) & 1u)) >> 16);
}

// Normalize rows of x (4 rows/block, wave per row); write fp32 (optional) + bf16 hi/lo.
__global__ __launch_bounds__(256) void prep_split_kernel(const float* __restrict__ x,
                                                         float* __restrict__ xn,
                                                         ushort_t* __restrict__ xh,
                                                         ushort_t* __restrict__ xl) {
  const int w = threadIdx.x >> 6, lane = threadIdx.x & 63;
  const size_t row = (size_t)blockIdx.x * 4 + w;
  const float4* src = (const float4*)(x + row * DDIM);
  float4 a = src[lane], b = src[lane + 64];
  float s = a.x*a.x + a.y*a.y + a.z*a.z + a.w*a.w
          + b.x*b.x + b.y*b.y + b.z*b.z + b.w*b.w;
  s = wave_sum(s);
  const float inv = 1.0f / fmaxf(sqrtf(s), 1e-12f);
  a.x *= inv; a.y *= inv; a.z *= inv; a.w *= inv;
  b.x *= inv; b.y *= inv; b.z *= inv; b.w *= inv;
  if (xn) {
    float4* dst = (float4*)(xn + row * DDIM);
    dst[lane] = a; dst[lane + 64] = b;
  }
  ushort4 h0, l0, h1, l1;
  split1(a.x, h0.x, l0.x); split1(a.y, h0.y, l0.y);
  split1(a.z, h0.z, l0.z); split1(a.w, h0.w, l0.w);
  split1(b.x, h1.x, l1.x); split1(b.y, h1.y, l1.y);
  split1(b.z, h1.z, l1.z); split1(b.w, h1.w, l1.w);
  ushort4* ph = (ushort4*)(xh + row * DDIM);
  ushort4* pl = (ushort4*)(xl + row * DDIM);
  ph[lane] = h0; ph[lane + 64] = h1;
  pl[lane] = l0; pl[lane + 64] = l1;
}

// Fragment read: 16B chunk at XOR-swizzled position, fetched as 2x ds_read_b64
// with quad-dependent half order -> conflict-free per half-wave. The induced
// k-permutation is identical for A and B fragments, so MFMA results unchanged.
__device__ __forceinline__ short8 frag_read(const ushort_t* base, int off16, int hsel) {
  short4v p = *(const short4v*)(base + off16 + hsel);
  short4v q = *(const short4v*)(base + off16 + (hsel ^ 4));
  return __builtin_shufflevector(p, q, 0, 1, 2, 3, 4, 5, 6, 7);
}

// bf16x2 (3-MFMA) GEMM over one N-chunk, tracking per-row top1 (v,i) + top2 (v).
__global__ __launch_bounds__(256, 2) void gemm3_kernel(
    const ushort_t* __restrict__ zh, const ushort_t* __restrict__ zl,
    const ushort_t* __restrict__ eh, const ushort_t* __restrict__ el,
    float* __restrict__ pv1, int* __restrict__ pi1, float* __restrict__ pv2) {
  __shared__ union {
    ushort_t stg[4][TM * BK];                            // Ah Al Bh Bl : 4 x 8 KB
    struct { float v1[TM][2]; float v2[TM][2]; int i1[TM][2]; } red;  // 3 KB
  } u;
  const int t = threadIdx.x;
  const int w = t >> 6;            // wave 0..3
  const int lane = t & 63;
  const int wm = w >> 1, wn = w & 1;
  const int col = lane & 15;
  const int quad = lane >> 4;
  const int chunk = blockIdx.x;
  const int row0 = blockIdx.y * TM;

  // staging source: lane l -> row (l>>2), swizzled chunk (l&3)^((l>>3)&3)
  const int swc = ((lane & 3) ^ ((lane >> 3) & 3)) * 8;  // ushort offset of 16B chunk
  const ushort_t* gsrcA = (w == 0 ? zh : zl)
      + (size_t)(row0 + (lane >> 2)) * DDIM + swc;
  const ushort_t* eb = (w == 2) ? eh : el;
  ushort_t* ldst = u.stg[w];

  // fragment-read swizzle: 16B chunk (quad ^ ((col>>1)&3)), half order by quad&1
  const int swr  = (quad ^ ((col >> 1) & 3)) * 8;
  const int hsel = (quad & 1) * 4;

  float tv1[16], tv2[16]; int ti1[16];
#pragma unroll
  for (int s = 0; s < 16; ++s) { tv1[s] = -3.0e38f; tv2[s] = -3.0e38f; ti1[s] = 0; }

  for (int ct = 0; ct < CHUNKN / TN; ++ct) {
    const int cbase = chunk * CHUNKN + ct * TN;
    const ushort_t* gsrc = (w < 2) ? gsrcA
        : eb + (size_t)(cbase + (lane >> 2)) * DDIM + swc;

    floatx4 acc[4][4];
    const floatx4 z4 = {0.f, 0.f, 0.f, 0.f};
#pragma unroll
    for (int i = 0; i < 4; ++i)
#pragma unroll
      for (int j = 0; j < 4; ++j) acc[i][j] = z4;

    for (int kt = 0; kt < DDIM / BK; ++kt) {
      __syncthreads();
#pragma unroll
      for (int i = 0; i < 8; ++i)
        ld2lds16(gsrc + (size_t)(i * 16) * DDIM + kt * BK, ldst + i * 512);
      __syncthreads();

      short8 ah[4], al[4], bh[4], bl[4];
#pragma unroll
      for (int i = 0; i < 4; ++i) {
        const int offA = (wm * 64 + i * 16 + col) * BK + swr;
        const int offB = (wn * 64 + i * 16 + col) * BK + swr;
        ah[i] = frag_read(u.stg[0], offA, hsel);
        al[i] = frag_read(u.stg[1], offA, hsel);
        bh[i] = frag_read(u.stg[2], offB, hsel);
        bl[i] = frag_read(u.stg[3], offB, hsel);
      }
#pragma unroll
      for (int i = 0; i < 4; ++i)
#pragma unroll
        for (int j = 0; j < 4; ++j) {
          acc[i][j] = mfma16(ah[i], bh[j], acc[i][j]);
          acc[i][j] = mfma16(ah[i], bl[j], acc[i][j]);
          acc[i][j] = mfma16(al[i], bh[j], acc[i][j]);
        }
    }

    int nj[4];
#pragma unroll
    for (int j = 0; j < 4; ++j) nj[j] = cbase + wn * 64 + j * 16 + col;
#pragma unroll
    for (int i = 0; i < 4; ++i)
#pragma unroll
      for (int r = 0; r < 4; ++r) {
        const int s = i * 4 + r;
#pragma unroll
        for (int j = 0; j < 4; ++j) {
          float v = acc[i][j][r];
          float mn = fminf(v, tv1[s]);
          bool gt = v > tv1[s];
          tv1[s] = gt ? v : tv1[s];
          ti1[s] = gt ? nj[j] : ti1[s];
          tv2[s] = fmaxf(tv2[s], mn);
        }
      }
  }

  // intra-wave top-2 reduce across the 16 col-lanes (lane bits 0..3)
#pragma unroll
  for (int off = 1; off < 16; off <<= 1) {
#pragma unroll
    for (int s = 0; s < 16; ++s) {
      float ov1 = __shfl_xor(tv1[s], off, 64);
      int   oi1 = __shfl_xor(ti1[s], off, 64);
      float ov2 = __shfl_xor(tv2[s], off, 64);
      float nv2 = fmaxf(fminf(tv1[s], ov1), fmaxf(tv2[s], ov2));
      if (ov1 > tv1[s] || (ov1 == tv1[s] && oi1 < ti1[s])) { tv1[s] = ov1; ti1[s] = oi1; }
      tv2[s] = nv2;
    }
  }
  __syncthreads();   // staging LDS reuse as reduction scratch
  if (col == 0) {
#pragma unroll
    for (int s = 0; s < 16; ++s) {
      const int rl = wm * 64 + (s >> 2) * 16 + quad * 4 + (s & 3);
      u.red.v1[rl][wn] = tv1[s];
      u.red.v2[rl][wn] = tv2[s];
      u.red.i1[rl][wn] = ti1[s];
    }
  }
  __syncthreads();
  if (t < TM) {
    float V1 = u.red.v1[t][0], V2 = u.red.v2[t][0];
    int   I1 = u.red.i1[t][0];
    float a1 = u.red.v1[t][1], a2 = u.red.v2[t][1];
    int   ai = u.red.i1[t][1];
    float nv2 = fmaxf(fminf(V1, a1), fmaxf(V2, a2));
    if (a1 > V1 || (a1 == V1 && ai < I1)) { V1 = a1; I1 = ai; }
    V2 = nv2;
    const size_t o = (size_t)chunk * BROWS + row0 + t;
    pv1[o] = V1; pi1[o] = I1; pv2[o] = V2;
  }
}

__global__ __launch_bounds__(256) void combine_kernel(
    const float* __restrict__ pv1, const int* __restrict__ pi1,
    const float* __restrict__ pv2, int* __restrict__ idxs,
    int* __restrict__ flagcnt, int* __restrict__ flaglist) {
  const int row = blockIdx.x * 256 + threadIdx.x;
  float V1 = pv1[row], V2 = pv2[row];
  int I1 = pi1[row];
#pragma unroll
  for (int c2 = 1; c2 < NCHUNK; ++c2) {
    const size_t o = (size_t)c2 * BROWS + row;
    float a1 = pv1[o], a2 = pv2[o];
    int ai = pi1[o];
    float nv2 = fmaxf(fminf(V1, a1), fmaxf(V2, a2));
    if (a1 > V1) { V1 = a1; I1 = ai; }   // ascending chunks: tie keeps lower index
    V2 = nv2;
  }
  idxs[row] = I1;
  if (V1 - V2 < MARGIN) {
    int p = atomicAdd(flagcnt, 1);
    flaglist[p] = row;
  }
}

// Exact fp32 rerank: one block per flagged row (strided), full 8192-code scan,
// block-local argmax with first-index tie-break, direct idxs write.
__global__ __launch_bounds__(256) void rerank_kernel(
    const float* __restrict__ z, const float* __restrict__ en,
    const int* __restrict__ flagcnt, const int* __restrict__ flaglist,
    int* __restrict__ idxs) {
  __shared__ float sZ[512];
  __shared__ float sv[256];
  __shared__ int   si[256];
  const int t = threadIdx.x;
  int nf = *flagcnt;
  if (nf > BROWS) nf = BROWS;
  for (int f = blockIdx.x; f < nf; f += gridDim.x) {
    const int row = flaglist[f];
    __syncthreads();
    if (t < 128) ((float4*)sZ)[t] = ((const float4*)(z + (size_t)row * DDIM))[t];
    __syncthreads();
    float bv = -3.0e38f; int bi = 0;
    for (int c = t; c < NCODES; c += 256) {
      const float4* ep = (const float4*)(en + (size_t)c * DDIM);
      float d = 0.0f;
#pragma unroll 16
      for (int k4 = 0; k4 < 128; ++k4) {
        float4 e4 = ep[k4];
        float4 zv = ((const float4*)sZ)[k4];
        d = fmaf(e4.x, zv.x, d); d = fmaf(e4.y, zv.y, d);
        d = fmaf(e4.z, zv.z, d); d = fmaf(e4.w, zv.w, d);
      }
      if (d > bv) { bv = d; bi = c; }   // ascending c: tie keeps lower index
    }
    sv[t] = bv; si[t] = bi;
    __syncthreads();
    for (int s2 = 128; s2 > 0; s2 >>= 1) {
      if (t < s2) {
        float ov = sv[t + s2]; int oi = si[t + s2];
        if (ov > sv[t] || (ov == sv[t] && oi < si[t])) { sv[t] = ov; si[t] = oi; }
      }
      __syncthreads();
    }
    if (t == 0) idxs[row] = si[0];
    __syncthreads();
  }
}

__global__ __launch_bounds__(256) void finalize_kernel(const float* __restrict__ z,
                                                       const float* __restrict__ en,
                                                       const int* __restrict__ idxs,
                                                       float* __restrict__ out_q,
                                                       float* __restrict__ out_i,
                                                       float* __restrict__ counts,
                                                       float* __restrict__ loss) {
  int w = threadIdx.x >> 6, lane = threadIdx.x & 63;
  int row = blockIdx.x * 4 + w;
  const float4* zr = (const float4*)(z + (size_t)row * DDIM);
  float4 a = zr[lane], b = zr[lane + 64];
  float s = a.x*a.x + a.y*a.y + a.z*a.z + a.w*a.w
          + b.x*b.x + b.y*b.y + b.z*b.z + b.w*b.w;
  s = wave_sum(s);
  float inv = 1.0f / fmaxf(sqrtf(s), 1e-12f);
  int k = idxs[row];
  const float4* qr = (const float4*)(en + (size_t)k * DDIM);
  float4 qa = qr[lane], qb = qr[lane + 64];
  float d = 0.0f;
  float4 oa, ob;
  {
    float zn;
    zn = a.x * inv; oa.x = zn + (qa.x - zn); d += (zn - qa.x) * (zn - qa.x);
    zn = a.y * inv; oa.y = zn + (qa.y - zn); d += (zn - qa.y) * (zn - qa.y);
    zn = a.z * inv; oa.z = zn + (qa.z - zn); d += (zn - qa.z) * (zn - qa.z);
    zn = a.w * inv; oa.w = zn + (qa.w - zn); d += (zn - qa.w) * (zn - qa.w);
    zn = b.x * inv; ob.x = zn + (qb.x - zn); d += (zn - qb.x) * (zn - qb.x);
    zn = b.y * inv; ob.y = zn + (qb.y - zn); d += (zn - qb.y) * (zn - qb.y);
    zn = b.z * inv; ob.z = zn + (qb.z - zn); d += (zn - qb.z) * (zn - qb.z);
    zn = b.w * inv; ob.w = zn + (qb.w - zn); d += (zn - qb.w) * (zn - qb.w);
  }
  float4* orow = (float4*)(out_q + (size_t)row * DDIM);
  orow[lane] = oa;
  orow[lane + 64] = ob;
  d = wave_sum(d);
  if (lane == 0) {
    atomicAdd(loss, d);
    atomicAdd(&counts[k], 1.0f);
    out_i[row] = (float)k;
  }
}

__global__ __launch_bounds__(256) void scalars_kernel(const float* __restrict__ counts,
                                                      const float* __restrict__ loss,
                                                      float* __restrict__ o) {
  __shared__ float se[256], su[256];
  int t = threadIdx.x;
  float ent = 0.0f, utl = 0.0f;
  for (int i = t; i < NCODES; i += 256) {
    float c = counts[i];
    float p = c * (1.0f / (float)BROWS);
    ent -= p * logf(p + 1e-10f);
    utl += (c > 0.0f) ? 1.0f : 0.0f;
  }
  se[t] = ent; su[t] = utl;
  __syncthreads();
  for (int s2 = 128; s2 > 0; s2 >>= 1) {
    if (t < s2) { se[t] += se[t + s2]; su[t] += su[t + s2]; }
    __syncthreads();
  }
  if (t == 0) {
    float mse = (*loss) * (1.0f / (float)(BROWS * DDIM));
    o[0] = 0.25f * mse;
    o[1] = mse;
    o[2] = expf(se[0]);
    o[3] = su[0] * (1.0f / (float)NCODES);
  }
}

// ---------- fallback (R1 fp32 path, used only if ws too small) ----------
__global__ __launch_bounds__(256) void fb_norm_rows(const float* __restrict__ e,
                                                    float* __restrict__ en) {
  int w = threadIdx.x >> 6, lane = threadIdx.x & 63;
  int row = blockIdx.x * 4 + w;
  const float4* src = (const float4*)(e + (size_t)row * DDIM);
  float4 a = src[lane], b = src[lane + 64];
  float s = a.x*a.x + a.y*a.y + a.z*a.z + a.w*a.w
          + b.x*b.x + b.y*b.y + b.z*b.z + b.w*b.w;
  s = wave_sum(s);
  float inv = 1.0f / fmaxf(sqrtf(s), 1e-12f);
  float4* dst = (float4*)(en + (size_t)row * DDIM);
  dst[lane] = make_float4(a.x*inv, a.y*inv, a.z*inv, a.w*inv);
  dst[lane + 64] = make_float4(b.x*inv, b.y*inv, b.z*inv, b.w*inv);
}

__global__ __launch_bounds__(256) void fb_gemm_argmax(const float* __restrict__ z,
                                                      const float* __restrict__ en,
                                                      int* __restrict__ out_idx) {
  __shared__ float As[16][TM + 4];
  __shared__ float Bs[16][TN + 4];
  __shared__ float rv[TM][16];
  __shared__ int   ri[TM][16];
  const int t = threadIdx.x;
  const int tx = t & 15, ty = t >> 4;
  const int row0 = blockIdx.x * TM;
  const int m = t >> 2, f4 = t & 3;
  float bestv[8]; int bestn[8];
#pragma unroll
  for (int i = 0; i < 8; ++i) { bestv[i] = -3.0e38f; bestn[i] = 0; }
  for (int ct = 0; ct < NCODES / TN; ++ct) {
    float acc[8][8];
#pragma unroll
    for (int i = 0; i < 8; ++i)
#pragma unroll
      for (int j = 0; j < 8; ++j) acc[i][j] = 0.0f;
    for (int kt = 0; kt < DDIM / 16; ++kt) {
      const int k0 = kt * 16;
      __syncthreads();
      {
        const float* zb = z + (size_t)(row0 + m) * DDIM + k0 + f4 * 4;
        float4 v0 = *(const float4*)zb;
        float4 v1 = *(const float4*)(zb + (size_t)64 * DDIM);
        const float* ebp = en + (size_t)(ct * TN + m) * DDIM + k0 + f4 * 4;
        float4 w0 = *(const float4*)ebp;
        float4 w1 = *(const float4*)(ebp + (size_t)64 * DDIM);
        const int kk = f4 * 4;
        As[kk+0][m] = v0.x; As[kk+1][m] = v0.y; As[kk+2][m] = v0.z; As[kk+3][m] = v0.w;
        As[kk+0][m+64] = v1.x; As[kk+1][m+64] = v1.y; As[kk+2][m+64] = v1.z; As[kk+3][m+64] = v1.w;
        Bs[kk+0][m] = w0.x; Bs[kk+1][m] = w0.y; Bs[kk+2][m] = w0.z; Bs[kk+3][m] = w0.w;
        Bs[kk+0][m+64] = w1.x; Bs[kk+1][m+64] = w1.y; Bs[kk+2][m+64] = w1.z; Bs[kk+3][m+64] = w1.w;
      }
      __syncthreads();
#pragma unroll
      for (int k = 0; k < 16; ++k) {
        float4 a0 = *(const float4*)&As[k][ty * 8];
        float4 a1 = *(const float4*)&As[k][ty * 8 + 4];
        float4 b0 = *(const float4*)&Bs[k][tx * 4];
        float4 b1 = *(const float4*)&Bs[k][64 + tx * 4];
        float a[8] = {a0.x,a0.y,a0.z,a0.w,a1.x,a1.y,a1.z,a1.w};
        float b[8] = {b0.x,b0.y,b0.z,b0.w,b1.x,b1.y,b1.z,b1.w};
#pragma unroll
        for (int i = 0; i < 8; ++i)
#pragma unroll
          for (int j = 0; j < 8; ++j) acc[i][j] = fmaf(a[i], b[j], acc[i][j]);
      }
    }
    const int nb = ct * TN;
#pragma unroll
    for (int i = 0; i < 8; ++i)
#pragma unroll
      for (int j = 0; j < 8; ++j) {
        int n = nb + ((j < 4) ? (tx * 4 + j) : (64 + tx * 4 + (j - 4)));
        if (acc[i][j] > bestv[i]) { bestv[i] = acc[i][j]; bestn[i] = n; }
      }
  }
#pragma unroll
  for (int i = 0; i < 8; ++i) { rv[ty*8+i][tx] = bestv[i]; ri[ty*8+i][tx] = bestn[i]; }
  __syncthreads();
  if (t < TM) {
    float bv = rv[t][0]; int bi = ri[t][0];
#pragma unroll
    for (int x = 1; x < 16; ++x) {
      float v = rv[t][x]; int n = ri[t][x];
      if (v > bv || (v == bv && n < bi)) { bv = v; bi = n; }
    }
    out_idx[row0 + t] = bi;
  }
}

extern "C" void kernel_launch(void* const* d_in, const int* in_sizes, int n_in,
                              void* d_out, int out_size, void* d_ws, size_t ws_size,
                              hipStream_t stream) {
  const float* z = (const float*)d_in[0];
  const float* e = (const float*)d_in[1];
  float* out = (float*)d_out;
  float* ws = (float*)d_ws;

  float* out_q = out;
  float* out_i = out + (size_t)BROWS * DDIM;
  float* out_s = out_i + BROWS;

  const size_t ENF = (size_t)NCODES * DDIM;   // 4,194,304
  const size_t ZNF = (size_t)BROWS * DDIM;    // 16,777,216

  // fast-path ws layout (float-unit offsets)
  size_t off = 0;
  float*    en      = ws + off;              off += ENF;
  ushort_t* enh     = (ushort_t*)(ws + off); off += ENF / 2;
  ushort_t* enl     = (ushort_t*)(ws + off); off += ENF / 2;
  ushort_t* zh      = (ushort_t*)(ws + off); off += ZNF / 2;
  ushort_t* zl      = (ushort_t*)(ws + off); off += ZNF / 2;
  float*    pv1     = ws + off;              off += (size_t)NCHUNK * BROWS;
  int*      pi1     = (int*)(ws + off);      off += (size_t)NCHUNK * BROWS;
  float*    pv2     = ws + off;              off += (size_t)NCHUNK * BROWS;
  int*      idxs    = (int*)(ws + off);      off += BROWS;
  int*      flaglist= (int*)(ws + off);      off += BROWS;
  float*    counts  = ws + off;              off += NCODES;
  float*    loss    = ws + off;              off += 1;
  int*      flagcnt = (int*)(ws + off);      off += 1;
  const size_t need_bytes = off * sizeof(float);

  if (ws_size >= need_bytes) {
    prep_split_kernel<<<NCODES / 4, 256, 0, stream>>>(e, en, enh, enl);
    prep_split_kernel<<<BROWS / 4, 256, 0, stream>>>(z, nullptr, zh, zl);
    hipMemsetAsync(counts, 0, (NCODES + 2) * sizeof(float), stream);
    dim3 g(NCHUNK, BROWS / TM);
    gemm3_kernel<<<g, 256, 0, stream>>>(zh, zl, enh, enl, pv1, pi1, pv2);
    combine_kernel<<<BROWS / 256, 256, 0, stream>>>(pv1, pi1, pv2, idxs, flagcnt, flaglist);
    rerank_kernel<<<256, 256, 0, stream>>>(z, en, flagcnt, flaglist, idxs);
    finalize_kernel<<<BROWS / 4, 256, 0, stream>>>(z, en, idxs, out_q, out_i, counts, loss);
    scalars_kernel<<<1, 256, 0, stream>>>(counts, loss, out_s);
  } else {
    // fallback: R1 fp32 path (~17 MB ws)
    float* fen    = ws;
    int*   fidx   = (int*)(fen + ENF);
    float* fcnt   = (float*)(fidx + BROWS);
    float* floss  = fcnt + NCODES;
    fb_norm_rows<<<NCODES / 4, 256, 0, stream>>>(e, fen);
    hipMemsetAsync(fcnt, 0, (NCODES + 1) * sizeof(float), stream);
    fb_gemm_argmax<<<BROWS / TM, 256, 0, stream>>>(z, fen, fidx);
    finalize_kernel<<<BROWS / 4, 256, 0, stream>>>(z, fen, fidx, out_q, out_i, fcnt, floss);
    scalars_kernel<<<1, 256, 0, stream>>>(fcnt, floss, out_s);
  }
}